// Round 2
// baseline (202.775 us; speedup 1.0000x reference)
//
#include <hip/hip_runtime.h>

// SelfAttention: B=4, T=2048, C=D=1024, causal, single head.
// Strategy: bf16 MFMA everywhere. Materialized S/P two-pass attention.
// ws layout (MB): [0 Qb 16][16 Kb 16][32 Vtb 16][48 xb 16][64 Wqb 2][66 Wkb 2]
//                 [68 Wvb 2][70 S fp32 64][134 P bf16 32] = 166 MB total.
// (Round 2 = round 1 resubmitted verbatim: round-1 bench died in infra,
//  no kernel signal was produced.)

using u16 = unsigned short;
typedef __attribute__((ext_vector_type(8))) short short8;
typedef __attribute__((ext_vector_type(4))) float f32x4;

__device__ __forceinline__ u16 f2b(float f) {
  unsigned u = __builtin_bit_cast(unsigned, f);
  u += 0x7fffu + ((u >> 16) & 1u);
  return (u16)(u >> 16);
}

__device__ __forceinline__ void async16(void* lds, const void* g) {
  __builtin_amdgcn_global_load_lds(
      (const __attribute__((address_space(1))) unsigned int*)g,
      (__attribute__((address_space(3))) unsigned int*)lds, 16, 0, 0);
}

__global__ __launch_bounds__(256) void cvt_kernel(const float* __restrict__ in,
                                                  u16* __restrict__ out, int n4) {
  const int i = blockIdx.x * 256 + threadIdx.x;
  if (i >= n4) return;
  const float4 v = reinterpret_cast<const float4*>(in)[i];
  ushort4 o;
  o.x = f2b(v.x); o.y = f2b(v.y); o.z = f2b(v.z); o.w = f2b(v.w);
  reinterpret_cast<ushort4*>(out)[i] = o;
}

// C[m][n] = sum_k A[m][k] * B[n][k]; 128x128 tile, BK=32, 4 waves (2x2 of 64x64).
// A-frag: row=lane&15, k=8*(lane>>4)+j ; B-frag: col=lane&15, k=8*(lane>>4)+j
// D-frag: col=lane&15, row=4*(lane>>4)+rr   (guide §3, HW-verified m89/m91)
template <typename Epi>
__device__ __forceinline__ void gemm_bt_tile(const u16* __restrict__ A, int lda,
                                             const u16* __restrict__ B, int ldb,
                                             int ksteps, Epi&& epi) {
  __shared__ __align__(16) u16 As[128 * 32];
  __shared__ __align__(16) u16 Bs[128 * 32];
  const int tid = threadIdx.x;
  const int lane = tid & 63;
  const int w = tid >> 6;
  const int wr = (w >> 1) << 6;
  const int wc = (w & 1) << 6;

  f32x4 zero = {0.f, 0.f, 0.f, 0.f};
  f32x4 acc[4][4];
#pragma unroll
  for (int i = 0; i < 4; ++i)
#pragma unroll
    for (int j = 0; j < 4; ++j) acc[i][j] = zero;

  // staging: thread t loads 8 bf16 (16B); row t>>2, col (t&3)*8 ; linear LDS
  const int sr = tid >> 2;
  const int sc = (tid & 3) << 3;
  const u16* ga0 = A + (size_t)sr * lda + sc;
  const u16* ga1 = A + (size_t)(sr + 64) * lda + sc;
  const u16* gb0 = B + (size_t)sr * ldb + sc;
  const u16* gb1 = B + (size_t)(sr + 64) * ldb + sc;
  u16* la0 = As + tid * 8;
  u16* la1 = As + 2048 + tid * 8;
  u16* lb0 = Bs + tid * 8;
  u16* lb1 = Bs + 2048 + tid * 8;

  const int foff = (lane & 15) * 32 + (lane >> 4) * 8;
  const u16* fa = As + wr * 32 + foff;
  const u16* fb = Bs + wc * 32 + foff;

  for (int ks = 0; ks < ksteps; ++ks) {
    __syncthreads();  // all waves done reading previous tile
    async16(la0, ga0);
    async16(la1, ga1);
    async16(lb0, gb0);
    async16(lb1, gb1);
    ga0 += 32; ga1 += 32; gb0 += 32; gb1 += 32;
    __syncthreads();  // vmcnt(0) drain: LDS tile ready
    short8 af[4], bf8[4];
#pragma unroll
    for (int i = 0; i < 4; ++i) af[i] = *(const short8*)(fa + (i << 9));
#pragma unroll
    for (int j = 0; j < 4; ++j) bf8[j] = *(const short8*)(fb + (j << 9));
#pragma unroll
    for (int i = 0; i < 4; ++i)
#pragma unroll
      for (int j = 0; j < 4; ++j)
        acc[i][j] = __builtin_amdgcn_mfma_f32_16x16x32_bf16(af[i], bf8[j],
                                                            acc[i][j], 0, 0, 0);
  }
  epi(acc, wr, wc, lane);
}

// bid 0..511: Q (x @ Wq^T, scaled 1/32); 512..1023: K; 1024..1535: Vt = Wv @ x^T
__global__ __launch_bounds__(256) void qkv_kernel(
    const u16* __restrict__ xb, const u16* __restrict__ Wqb,
    const u16* __restrict__ Wkb, const u16* __restrict__ Wvb,
    const float* __restrict__ bq, const float* __restrict__ bk,
    const float* __restrict__ bv, u16* __restrict__ Qb, u16* __restrict__ Kb,
    u16* __restrict__ Vtb) {
  const int bid = blockIdx.x;
  const int z = bid >> 9;
  const int r = bid & 511;
  if (z < 2) {
    const int mt = r >> 3, nt = r & 7;  // 64 x 8 tiles over (8192 x 1024)
    const u16* W = z ? Wkb : Wqb;
    const float* bias = z ? bk : bq;
    u16* out = z ? Kb : Qb;
    const float scale = z ? 1.0f : 0.03125f;  // Q pre-scaled by 1/sqrt(1024)
    gemm_bt_tile(
        xb + (size_t)mt * 128 * 1024, 1024, W + (size_t)nt * 128 * 1024, 1024, 32,
        [&](f32x4(&acc)[4][4], int wr, int wc, int lane) {
          const int r0 = mt * 128 + wr + ((lane >> 4) << 2);
          const int c0 = nt * 128 + wc + (lane & 15);
#pragma unroll
          for (int i = 0; i < 4; ++i)
#pragma unroll
            for (int j = 0; j < 4; ++j) {
              const int col = c0 + j * 16;
              const float bb = bias[col];
#pragma unroll
              for (int rr = 0; rr < 4; ++rr)
                out[(size_t)(r0 + i * 16 + rr) * 1024 + col] =
                    f2b((acc[i][j][rr] + bb) * scale);
            }
        });
  } else {
    const int mt = r >> 6, nt = r & 63;  // 8 x 64 tiles over (1024 x 8192)
    gemm_bt_tile(
        Wvb + (size_t)mt * 128 * 1024, 1024, xb + (size_t)nt * 128 * 1024, 1024, 32,
        [&](f32x4(&acc)[4][4], int wr, int wc, int lane) {
          const int r0 = mt * 128 + wr + ((lane >> 4) << 2);
          const int c0 = nt * 128 + wc + (lane & 15);
#pragma unroll
          for (int i = 0; i < 4; ++i)
#pragma unroll
            for (int rr = 0; rr < 4; ++rr) {
              const int row = r0 + i * 16 + rr;  // d index
              const float bb = bv[row];
#pragma unroll
              for (int j = 0; j < 4; ++j)
                Vtb[(size_t)row * 8192 + c0 + j * 16] = f2b(acc[i][j][rr] + bb);
            }
        });
  }
}

// lower-triangle tiles only: grid (136, 4)
__global__ __launch_bounds__(256) void score_kernel(const u16* __restrict__ Qb,
                                                    const u16* __restrict__ Kb,
                                                    float* __restrict__ S) {
  const int b = blockIdx.y;
  const int t = blockIdx.x;
  int qt = 0;
  while ((qt + 1) * (qt + 2) / 2 <= t) ++qt;
  const int kt = t - (qt * (qt + 1)) / 2;
  const u16* A = Qb + ((size_t)b * 2048 + qt * 128) * 1024;
  const u16* Bp = Kb + ((size_t)b * 2048 + kt * 128) * 1024;
  float* Sb = S + (size_t)b * 2048 * 2048;
  gemm_bt_tile(A, 1024, Bp, 1024, 32,
               [&](f32x4(&acc)[4][4], int wr, int wc, int lane) {
                 const int r0 = qt * 128 + wr + ((lane >> 4) << 2);
                 const int c0 = kt * 128 + wc + (lane & 15);
#pragma unroll
                 for (int i = 0; i < 4; ++i)
#pragma unroll
                   for (int j = 0; j < 4; ++j)
#pragma unroll
                     for (int rr = 0; rr < 4; ++rr)
                       Sb[(size_t)(r0 + i * 16 + rr) * 2048 + c0 + j * 16] =
                           acc[i][j][rr];
               });
}

// one block per row; causal softmax over k<=q; zero-fill to 128-boundary
__global__ __launch_bounds__(256) void softmax_kernel(const float* __restrict__ S,
                                                      u16* __restrict__ P) {
  __shared__ float redm[4], reds[4];
  const int rowid = blockIdx.x;
  const int b = rowid >> 11;
  const int q = rowid & 2047;
  const float* Srow = S + ((size_t)b * 2048 + q) * 2048;
  u16* Prow = P + ((size_t)b * 2048 + q) * 2048;
  const int L = q + 1;
  const int Lpad = ((q >> 7) + 1) << 7;
  const int tid = threadIdx.x;
  float v[8];
  float m = -1e30f;
#pragma unroll
  for (int j = 0; j < 8; ++j) {
    const int k = tid + (j << 8);
    v[j] = (k < L) ? Srow[k] : -1e30f;
    m = fmaxf(m, v[j]);
  }
#pragma unroll
  for (int o = 32; o > 0; o >>= 1) m = fmaxf(m, __shfl_xor(m, o));
  if ((tid & 63) == 0) redm[tid >> 6] = m;
  __syncthreads();
  m = fmaxf(fmaxf(redm[0], redm[1]), fmaxf(redm[2], redm[3]));
  float s = 0.f;
#pragma unroll
  for (int j = 0; j < 8; ++j) {
    const int k = tid + (j << 8);
    const float e = (k < L) ? __expf(v[j] - m) : 0.f;
    v[j] = e;
    s += e;
  }
#pragma unroll
  for (int o = 32; o > 0; o >>= 1) s += __shfl_xor(s, o);
  if ((tid & 63) == 0) reds[tid >> 6] = s;
  __syncthreads();
  s = reds[0] + reds[1] + reds[2] + reds[3];
  const float inv = 1.0f / s;
#pragma unroll
  for (int j = 0; j < 8; ++j) {
    const int k = tid + (j << 8);
    if (k < Lpad) Prow[k] = (k < L) ? f2b(v[j] * inv) : (u16)0;
  }
}

// O = P @ V using Vt[d][t]; K-loop truncated by causality
__global__ __launch_bounds__(256) void pv_kernel(const u16* __restrict__ P,
                                                 const u16* __restrict__ Vtb,
                                                 float* __restrict__ O) {
  const int bid = blockIdx.x;  // 512 = 4b x 16qt x 8dt
  const int b = bid >> 7;
  const int r = bid & 127;
  const int qt = r >> 3, dt = r & 7;
  const u16* A = P + (size_t)b * 2048 * 2048 + (size_t)qt * 128 * 2048;
  const u16* Bp = Vtb + (size_t)dt * 128 * 8192 + b * 2048;
  float* Ob = O + (size_t)b * 2048 * 1024;
  gemm_bt_tile(A, 2048, Bp, 8192, (qt + 1) * 4,
               [&](f32x4(&acc)[4][4], int wr, int wc, int lane) {
                 const int r0 = qt * 128 + wr + ((lane >> 4) << 2);
                 const int c0 = dt * 128 + wc + (lane & 15);
#pragma unroll
                 for (int i = 0; i < 4; ++i)
#pragma unroll
                   for (int j = 0; j < 4; ++j)
#pragma unroll
                     for (int rr = 0; rr < 4; ++rr)
                       Ob[(size_t)(r0 + i * 16 + rr) * 1024 + c0 + j * 16] =
                           acc[i][j][rr];
               });
}

extern "C" void kernel_launch(void* const* d_in, const int* in_sizes, int n_in,
                              void* d_out, int out_size, void* d_ws, size_t ws_size,
                              hipStream_t stream) {
  const float* x = (const float*)d_in[0];
  const float* Wq = (const float*)d_in[1];
  const float* bq = (const float*)d_in[2];
  const float* Wk = (const float*)d_in[3];
  const float* bk = (const float*)d_in[4];
  const float* Wv = (const float*)d_in[5];
  const float* bv = (const float*)d_in[6];
  float* out = (float*)d_out;
  char* ws = (char*)d_ws;
  u16* Qb = (u16*)(ws);
  u16* Kb = (u16*)(ws + (16u << 20));
  u16* Vtb = (u16*)(ws + (32u << 20));
  u16* xb = (u16*)(ws + (48u << 20));
  u16* Wqb = (u16*)(ws + (64u << 20));
  u16* Wkb = (u16*)(ws + (66u << 20));
  u16* Wvb = (u16*)(ws + (68u << 20));
  float* S = (float*)(ws + (70u << 20));
  u16* P = (u16*)(ws + (134u << 20));

  cvt_kernel<<<8192, 256, 0, stream>>>(x, xb, (8192 * 1024) / 4);
  cvt_kernel<<<1024, 256, 0, stream>>>(Wq, Wqb, (1024 * 1024) / 4);
  cvt_kernel<<<1024, 256, 0, stream>>>(Wk, Wkb, (1024 * 1024) / 4);
  cvt_kernel<<<1024, 256, 0, stream>>>(Wv, Wvb, (1024 * 1024) / 4);
  qkv_kernel<<<1536, 256, 0, stream>>>(xb, Wqb, Wkb, Wvb, bq, bk, bv, Qb, Kb, Vtb);
  score_kernel<<<dim3(136, 4), 256, 0, stream>>>(Qb, Kb, S);
  softmax_kernel<<<8192, 256, 0, stream>>>(S, P);
  pv_kernel<<<512, 256, 0, stream>>>(P, Vtb, out);
}